// Round 1
// 1125.904 us; speedup vs baseline: 1.0640x; 1.0640x over previous
//
#include <hip/hip_runtime.h>

typedef __bf16 bf16_t;
typedef bf16_t bf16x8 __attribute__((ext_vector_type(8)));
typedef bf16_t bf16x4 __attribute__((ext_vector_type(4)));
typedef float f32x4 __attribute__((ext_vector_type(4)));

#define DEVI static __device__ __forceinline__

constexpr int BB = 64;
constexpr int NN = 4096;
constexpr int DD = 256;
constexpr int KS = 11;     // real slots
constexpr int KP = 16;     // padded slots (MFMA tile)
constexpr int HH = 512;
constexpr float EPS_A = 1e-8f;
constexpr float LNEPS = 1e-5f;
constexpr float SCALE = 0.0625f;   // 256^-0.5
constexpr int MR = BB * KP;        // 1024 padded slot rows
constexpr int LDA = 264;           // LDS bf16 row stride (528B, 16B-aligned, bank-spread)
constexpr int LDH = 520;           // LDS stride for 512-wide h1 tile

DEVI float sigm(float x) { return 1.f / (1.f + __expf(-x)); }

// ---------------- prelude: f32 -> bf16 weight casts (Whh, W1, W2) ----------------
__global__ void conv3_k(const float* __restrict__ a, const float* __restrict__ b,
                        const float* __restrict__ c2,
                        bf16_t* da, bf16_t* db, bf16_t* dc) {
  int i = blockIdx.x * 256 + threadIdx.x;   // 458752 total
  const float* s; bf16_t* d; int o;
  if      (i < 196608) { s = a;  d = da; o = i; }
  else if (i < 327680) { s = b;  d = db; o = i - 196608; }
  else                 { s = c2; d = dc; o = i - 327680; }
  d[o] = (bf16_t)s[o];
}

// ---------------- prelude: GW[f,e] = SCALE * sum_d Wk[d,f]*Wq[d,e]  (q2 = sln @ GW^T) ----------------
__global__ void gw_k(const float* __restrict__ Wq, const float* __restrict__ Wk,
                     bf16_t* __restrict__ GW) {
  const int cc = blockIdx.x, e = threadIdx.x;
  float acc = 0.f;
  for (int d = 0; d < 256; d++) acc = fmaf(Wk[d * 256 + cc], Wq[d * 256 + e], acc);
  GW[cc * 256 + e] = (bf16_t)(acc * SCALE);
}

// ---------------- prelude: Wihv[c,e] = sum_d W_ih[c,d]*Wv[d,e]  (gi = updN @ Wihv^T + b_ih) ----------------
__global__ void wihv_k(const float* __restrict__ Wih, const float* __restrict__ Wv,
                       bf16_t* __restrict__ Wihv) {
  const int cc = blockIdx.x, e = threadIdx.x;   // 768 blocks
  float acc = 0.f;
  for (int d = 0; d < 256; d++) acc = fmaf(Wih[cc * 256 + d], Wv[d * 256 + e], acc);
  Wihv[cc * 256 + e] = (bf16_t)acc;
}

// ---------------- prelude: pad slots_init (B,11,D) -> (B,16,D) f32 ----------------
__global__ void init_slots_k(const float* __restrict__ si, float* __restrict__ slots) {
  int i = blockIdx.x * 256 + threadIdx.x;   // over MR*DD
  int d = i & 255, row = i >> 8, b = row >> 4, k = row & 15;
  slots[i] = (k < KS) ? si[((long)b * KS + k) * DD + d] : 0.f;
}

// ---------------- LN(inputs) -> x_bf [b][n][e]  AND  xT_bf [b][e][n] (LDS transpose) ----------------
__global__ __launch_bounds__(256) void ln_tr_k(const float* __restrict__ x,
                                               const float* __restrict__ w,
                                               const float* __restrict__ bsk,
                                               bf16_t* __restrict__ xo,
                                               bf16_t* __restrict__ xto) {
  __shared__ bf16_t ts[32 * LDA];
  const int b = blockIdx.x >> 7, nt = blockIdx.x & 127;   // 32 rows per block
  const int tid = threadIdx.x, g = tid >> 3, h = tid & 7; // 8 threads per row
  const long row = (long)b * NN + nt * 32 + g;
  const float4* src = (const float4*)(x + row * DD) + h * 8;
  float4 v[8];
  float s = 0.f, s2 = 0.f;
#pragma unroll
  for (int j = 0; j < 8; j++) {
    v[j] = src[j];
    s += v[j].x + v[j].y + v[j].z + v[j].w;
    s2 += v[j].x * v[j].x + v[j].y * v[j].y + v[j].z * v[j].z + v[j].w * v[j].w;
  }
#pragma unroll
  for (int off = 1; off < 8; off <<= 1) { s += __shfl_xor(s, off); s2 += __shfl_xor(s2, off); }
  const float mean = s * (1.f / DD);
  const float var = s2 * (1.f / DD) - mean * mean;
  const float rstd = rsqrtf(var + LNEPS);
  const float4* w4 = (const float4*)w + h * 8;
  const float4* b4 = (const float4*)bsk + h * 8;
  bf16x8* xrow = (bf16x8*)(xo + row * DD) + h * 4;
#pragma unroll
  for (int j2 = 0; j2 < 4; j2++) {
    float4 a0 = v[2 * j2], a1 = v[2 * j2 + 1];
    float4 w0 = w4[2 * j2], w1 = w4[2 * j2 + 1];
    float4 bb0 = b4[2 * j2], bb1 = b4[2 * j2 + 1];
    bf16x8 o;
    o[0] = (bf16_t)((a0.x - mean) * rstd * w0.x + bb0.x);
    o[1] = (bf16_t)((a0.y - mean) * rstd * w0.y + bb0.y);
    o[2] = (bf16_t)((a0.z - mean) * rstd * w0.z + bb0.z);
    o[3] = (bf16_t)((a0.w - mean) * rstd * w0.w + bb0.w);
    o[4] = (bf16_t)((a1.x - mean) * rstd * w1.x + bb1.x);
    o[5] = (bf16_t)((a1.y - mean) * rstd * w1.y + bb1.y);
    o[6] = (bf16_t)((a1.z - mean) * rstd * w1.z + bb1.z);
    o[7] = (bf16_t)((a1.w - mean) * rstd * w1.w + bb1.w);
    xrow[j2] = o;
    *(bf16x8*)(ts + g * LDA + h * 32 + j2 * 8) = o;
  }
  __syncthreads();
#pragma unroll
  for (int p = 0; p < 4; p++) {
    const int e = p * 64 + (tid >> 2), nc = (tid & 3) * 8;
    bf16x8 o2;
#pragma unroll
    for (int j = 0; j < 8; j++) o2[j] = ts[(nc + j) * LDA + e];
    *(bf16x8*)(xto + ((long)b * DD + e) * NN + nt * 32 + nc) = o2;
  }
}

// ---------------- fused dots+softmax:  att_bf [b][i][n], rowsum atomics ----------------
// dots[b,i,n] = sum_e q2[b,i,e] * x[b,n,e]   (SCALE folded into GW -> q2)
__global__ __launch_bounds__(256) void attn1_k(const bf16_t* __restrict__ q2,
                                               const bf16_t* __restrict__ xb,
                                               bf16_t* __restrict__ att,
                                               float* __restrict__ rowsum) {
  const int b = blockIdx.x >> 3, strip = blockIdx.x & 7;
  const int wv = threadIdx.x >> 6, lane = threadIdx.x & 63, c = lane & 15, qq = lane >> 4;
  const int n0 = strip * 512 + wv * 128;
  const bf16_t* qp = q2 + (long)b * KP * DD;
  bf16x8 af[8];
#pragma unroll
  for (int kc = 0; kc < 8; kc++) af[kc] = *(const bf16x8*)(qp + c * DD + kc * 32 + qq * 8);
  const bf16_t* xp = xb + (long)b * NN * DD;
  bf16_t* ap = att + (long)b * KP * NN;
  float rs[4] = {0.f, 0.f, 0.f, 0.f};
#pragma unroll
  for (int nt = 0; nt < 8; nt++) {
    f32x4 acc = (f32x4){0.f, 0.f, 0.f, 0.f};
    const bf16_t* bp = xp + (long)(n0 + nt * 16 + c) * DD + qq * 8;
#pragma unroll
    for (int kc = 0; kc < 8; kc++)
      acc = __builtin_amdgcn_mfma_f32_16x16x32_bf16(af[kc], *(const bf16x8*)(bp + kc * 32), acc, 0, 0, 0);
    // softmax over i (= qq*4+r, spread across the 4 qq lane-groups)
    float mx = -1e30f;
#pragma unroll
    for (int r = 0; r < 4; r++) if (qq * 4 + r < KS) mx = fmaxf(mx, acc[r]);
    mx = fmaxf(mx, __shfl_xor(mx, 16)); mx = fmaxf(mx, __shfl_xor(mx, 32));
    float ev[4], sum = 0.f;
#pragma unroll
    for (int r = 0; r < 4; r++) { ev[r] = (qq * 4 + r < KS) ? __expf(acc[r] - mx) : 0.f; sum += ev[r]; }
    sum += __shfl_xor(sum, 16); sum += __shfl_xor(sum, 32);
    const float inv = 1.f / sum;
    const int n = n0 + nt * 16 + c;
#pragma unroll
    for (int r = 0; r < 4; r++) {
      float a = (qq * 4 + r < KS) ? ev[r] * inv + EPS_A : 0.f;
      rs[r] += a;
      ap[(qq * 4 + r) * NN + n] = (bf16_t)a;
    }
  }
#pragma unroll
  for (int r = 0; r < 4; r++) {
#pragma unroll
    for (int off = 8; off >= 1; off >>= 1) rs[r] += __shfl_xor(rs[r], off);
  }
  if (c == 0) {
#pragma unroll
    for (int r = 0; r < 4; r++)
      if (qq * 4 + r < KS) atomicAdd(&rowsum[b * KP + qq * 4 + r], rs[r]);
  }
}

// ---------------- updR += attn @ x  (contracts n; reads xT [b][e][n]; K-split over N, atomic f32) ----------------
__global__ void updates_k(const bf16_t* __restrict__ att, const bf16_t* __restrict__ xT,
                          float* __restrict__ upd) {
  const int b = blockIdx.x >> 3, ksp = blockIdx.x & 7;
  const int wvi = threadIdx.x >> 6, lane = threadIdx.x & 63, c = lane & 15, q = lane >> 4;
  const int d0 = wvi * 64;
  const bf16_t* ab = att + (long)b * KP * NN;
  const bf16_t* vb = xT + (long)b * DD * NN;
  f32x4 acc[4];
#pragma unroll
  for (int dt = 0; dt < 4; dt++) acc[dt] = (f32x4){0.f, 0.f, 0.f, 0.f};
  const int j0b = ksp * 512;
  for (int j0 = j0b; j0 < j0b + 512; j0 += 32) {
    bf16x8 a = *(const bf16x8*)(ab + c * NN + j0 + q * 8);
#pragma unroll
    for (int dt = 0; dt < 4; dt++) {
      bf16x8 bb = *(const bf16x8*)(vb + (long)(d0 + dt * 16 + c) * NN + j0 + q * 8);
      acc[dt] = __builtin_amdgcn_mfma_f32_16x16x32_bf16(a, bb, acc[dt], 0, 0, 0);
    }
  }
  float* ub = upd + (long)b * KP * DD;
#pragma unroll
  for (int dt = 0; dt < 4; dt++)
#pragma unroll
    for (int r = 0; r < 4; r++)
      atomicAdd(&ub[(q * 4 + r) * DD + d0 + dt * 16 + c], acc[dt][r]);
}

// ---------------- row LayerNorm over the 16x256 register tile -> bf16 LDS tile ----------------
DEVI void row_ln(float (&v)[4][4], const float* __restrict__ lw, const float* __restrict__ lb,
                 bf16_t* dst, float (*red)[4][16], int w, int c, int qq, int E0) {
  float ps[4], pq[4];
#pragma unroll
  for (int r = 0; r < 4; r++) {
    ps[r] = v[0][r] + v[1][r] + v[2][r] + v[3][r];
    pq[r] = v[0][r] * v[0][r] + v[1][r] * v[1][r] + v[2][r] * v[2][r] + v[3][r] * v[3][r];
  }
#pragma unroll
  for (int r = 0; r < 4; r++) {
#pragma unroll
    for (int off = 1; off < 16; off <<= 1) {
      ps[r] += __shfl_xor(ps[r], off);
      pq[r] += __shfl_xor(pq[r], off);
    }
  }
  if (c == 0) {
#pragma unroll
    for (int r = 0; r < 4; r++) { red[0][w][qq * 4 + r] = ps[r]; red[1][w][qq * 4 + r] = pq[r]; }
  }
  __syncthreads();
#pragma unroll
  for (int r = 0; r < 4; r++) {
    const int R = qq * 4 + r;
    const float m = (red[0][0][R] + red[0][1][R] + red[0][2][R] + red[0][3][R]) * (1.f / DD);
    const float va = (red[1][0][R] + red[1][1][R] + red[1][2][R] + red[1][3][R]) * (1.f / DD) - m * m;
    const float rstd = rsqrtf(va + LNEPS);
#pragma unroll
    for (int et = 0; et < 4; et++) {
      const int col = E0 + et * 16 + c;
      dst[R * LDA + col] = (bf16_t)((v[et][r] - m) * rstd * lw[col] + lb[col]);
    }
  }
  __syncthreads();
}

// ---------------- mega per-iteration kernel: one block per batch ----------------
// PHASE 0: LN_s(slots) -> q2; zero updR/rowsum.
// PHASE 1: finalize(updR/rowsum) -> GRU (gi via Wihv fold) -> LN_p -> MLP+residual -> slots;
//          then (if !last) LN_s -> q2, zero scratch; if last, write d_out (B,11,256).
template <int PHASE>
__global__ __launch_bounds__(256, 1) void iter_k(
    float* __restrict__ updR, float* __restrict__ rowsum, float* __restrict__ slots,
    const float* __restrict__ b_ih, const float* __restrict__ b_hh,
    const bf16_t* __restrict__ Wihv, const bf16_t* __restrict__ Whh,
    const bf16_t* __restrict__ W1, const float* __restrict__ b1,
    const bf16_t* __restrict__ W2, const float* __restrict__ b2,
    const float* __restrict__ lpw, const float* __restrict__ lpb,
    const float* __restrict__ lsw, const float* __restrict__ lsb,
    const bf16_t* __restrict__ GW, bf16_t* __restrict__ q2,
    float* __restrict__ dout, int last) {
  __shared__ bf16_t uN[16 * LDA];
  __shared__ bf16_t sS[16 * LDA];
  __shared__ bf16_t pS[16 * LDA];      // LN_p output; later reused for LN_s output
  __shared__ bf16_t h1S[16 * LDH];
  __shared__ float red[2][4][16];
  const int b = blockIdx.x;
  const int tid = threadIdx.x, w = tid >> 6, lane = tid & 63, c = lane & 15, qq = lane >> 4;
  const int E0 = w * 64;
  const long base = (long)b * 16 * 256;
  float sf[4][4];   // value at (row = qq*4+r, col = E0+et*16+c)

  if (PHASE == 1) {
    // ---- stage A: finalize updates + stage A-operands to LDS ----
    float rsv[4];
#pragma unroll
    for (int r = 0; r < 4; r++) rsv[r] = rowsum[b * 16 + qq * 4 + r];
    float sp[4][4];
#pragma unroll
    for (int et = 0; et < 4; et++) {
#pragma unroll
      for (int r = 0; r < 4; r++) {
        const int R = qq * 4 + r, col = E0 + et * 16 + c;
        const long gidx = base + (long)R * 256 + col;
        float u = updR[gidx]; updR[gidx] = 0.f;      // re-zero for next iteration's atomics
        float sv = slots[gidx];
        sp[et][r] = sv;
        float un = (R < KS) ? u / rsv[r] : 0.f;      // pad rows: rowsum==0, mask the NaN
        uN[R * LDA + col] = (bf16_t)un;
        sS[R * LDA + col] = (bf16_t)sv;
      }
    }
    __syncthreads();
    // ---- stage B+C: gi = updN@Wihv^T + b_ih ; gh = slots@Whh^T + b_hh ; GRU pointwise ----
    bf16x8 afu[8], afs[8];
#pragma unroll
    for (int kc = 0; kc < 8; kc++) {
      afu[kc] = *(const bf16x8*)(uN + c * LDA + kc * 32 + qq * 8);
      afs[kc] = *(const bf16x8*)(sS + c * LDA + kc * 32 + qq * 8);
    }
    float rg[4][4], zg[4][4];
#pragma unroll
    for (int g = 0; g < 3; g++) {
      f32x4 ai[4], ah[4];
#pragma unroll
      for (int et = 0; et < 4; et++) { ai[et] = (f32x4){0,0,0,0}; ah[et] = (f32x4){0,0,0,0}; }
#pragma unroll
      for (int et = 0; et < 4; et++) {
        const bf16_t* wi = Wihv + ((long)(g * 256 + E0 + et * 16 + c)) * 256 + qq * 8;
        const bf16_t* wh = Whh + ((long)(g * 256 + E0 + et * 16 + c)) * 256 + qq * 8;
#pragma unroll
        for (int kc = 0; kc < 8; kc++) {
          ai[et] = __builtin_amdgcn_mfma_f32_16x16x32_bf16(afu[kc], *(const bf16x8*)(wi + kc * 32), ai[et], 0, 0, 0);
          ah[et] = __builtin_amdgcn_mfma_f32_16x16x32_bf16(afs[kc], *(const bf16x8*)(wh + kc * 32), ah[et], 0, 0, 0);
        }
      }
#pragma unroll
      for (int et = 0; et < 4; et++) {
        const int col = E0 + et * 16 + c;
        const float bi = b_ih[g * 256 + col], bh = b_hh[g * 256 + col];
#pragma unroll
        for (int r = 0; r < 4; r++) {
          const float xi = ai[et][r] + bi, xh = ah[et][r] + bh;
          if (g == 0) rg[et][r] = sigm(xi + xh);
          else if (g == 1) zg[et][r] = sigm(xi + xh);
          else {
            const float nh = tanhf(xi + rg[et][r] * xh);
            sf[et][r] = (1.f - zg[et][r]) * nh + zg[et][r] * sp[et][r];
          }
        }
      }
    }
    // ---- LN_p -> pS ----
    row_ln(sf, lpw, lpb, pS, red, w, c, qq, E0);
    // ---- stage D: h1 = relu(p@W1^T + b1) ----
    bf16x8 afp[8];
#pragma unroll
    for (int kc = 0; kc < 8; kc++) afp[kc] = *(const bf16x8*)(pS + c * LDA + kc * 32 + qq * 8);
#pragma unroll
    for (int ht = 0; ht < 8; ht++) {
      f32x4 a0 = (f32x4){0, 0, 0, 0};
      const int colh = w * 128 + ht * 16 + c;
      const bf16_t* w1p = W1 + (long)colh * 256 + qq * 8;
#pragma unroll
      for (int kc = 0; kc < 8; kc++)
        a0 = __builtin_amdgcn_mfma_f32_16x16x32_bf16(afp[kc], *(const bf16x8*)(w1p + kc * 32), a0, 0, 0, 0);
      const float bv = b1[colh];
#pragma unroll
      for (int r = 0; r < 4; r++) h1S[(qq * 4 + r) * LDH + colh] = (bf16_t)fmaxf(a0[r] + bv, 0.f);
    }
    __syncthreads();
    // ---- stage E: slots = s_new + h1@W2^T + b2 ----
    f32x4 ao[4];
#pragma unroll
    for (int et = 0; et < 4; et++) ao[et] = (f32x4){0, 0, 0, 0};
#pragma unroll
    for (int kc2 = 0; kc2 < 16; kc2++) {
      const bf16x8 afh = *(const bf16x8*)(h1S + c * LDH + kc2 * 32 + qq * 8);
#pragma unroll
      for (int et = 0; et < 4; et++)
        ao[et] = __builtin_amdgcn_mfma_f32_16x16x32_bf16(
            afh, *(const bf16x8*)(W2 + (long)(E0 + et * 16 + c) * 512 + kc2 * 32 + qq * 8), ao[et], 0, 0, 0);
    }
#pragma unroll
    for (int et = 0; et < 4; et++)
#pragma unroll
      for (int r = 0; r < 4; r++)
        sf[et][r] = ao[et][r] + b2[E0 + et * 16 + c] + sf[et][r];
    if (last) {
#pragma unroll
      for (int et = 0; et < 4; et++)
#pragma unroll
        for (int r = 0; r < 4; r++) {
          const int R = qq * 4 + r;
          if (R < KS) dout[((long)b * KS + R) * 256 + E0 + et * 16 + c] = sf[et][r];
        }
      return;
    }
#pragma unroll
    for (int et = 0; et < 4; et++)
#pragma unroll
      for (int r = 0; r < 4; r++)
        slots[base + (long)(qq * 4 + r) * 256 + E0 + et * 16 + c] = sf[et][r];
  } else {
    // PHASE 0: load initial slots; zero updR
#pragma unroll
    for (int et = 0; et < 4; et++) {
#pragma unroll
      for (int r = 0; r < 4; r++) {
        const long gidx = base + (long)(qq * 4 + r) * 256 + E0 + et * 16 + c;
        sf[et][r] = slots[gidx];
        updR[gidx] = 0.f;
      }
    }
  }
  // ---- stage F (common): LN_s -> q2 = sln @ GW^T ; zero rowsum ----
  row_ln(sf, lsw, lsb, pS, red, w, c, qq, E0);
  bf16x8 afq[8];
#pragma unroll
  for (int kc = 0; kc < 8; kc++) afq[kc] = *(const bf16x8*)(pS + c * LDA + kc * 32 + qq * 8);
#pragma unroll
  for (int et = 0; et < 4; et++) {
    f32x4 aq = (f32x4){0, 0, 0, 0};
    const bf16_t* gp = GW + (long)(E0 + et * 16 + c) * 256 + qq * 8;
#pragma unroll
    for (int kc = 0; kc < 8; kc++)
      aq = __builtin_amdgcn_mfma_f32_16x16x32_bf16(afq[kc], *(const bf16x8*)(gp + kc * 32), aq, 0, 0, 0);
#pragma unroll
    for (int r = 0; r < 4; r++)
      q2[base + (long)(qq * 4 + r) * 256 + E0 + et * 16 + c] = (bf16_t)aq[r];
  }
  if (tid < 16) rowsum[b * 16 + tid] = 0.f;
}

extern "C" void kernel_launch(void* const* d_in, const int* in_sizes, int n_in, void* d_out,
                              int out_size, void* d_ws, size_t ws_size, hipStream_t stream) {
  (void)in_sizes; (void)n_in; (void)out_size; (void)ws_size;
  const float* inputs = (const float*)d_in[0];
  const float* slots_in = (const float*)d_in[1];
  const float* ln_f_w = (const float*)d_in[2];
  const float* ln_f_b = (const float*)d_in[3];
  const float* ln_s_w = (const float*)d_in[4];
  const float* ln_s_b = (const float*)d_in[5];
  const float* ln_p_w = (const float*)d_in[6];
  const float* ln_p_b = (const float*)d_in[7];
  const float* Wq = (const float*)d_in[8];
  const float* Wk = (const float*)d_in[9];
  const float* Wv = (const float*)d_in[10];
  const float* W_ih = (const float*)d_in[11];
  const float* b_ih = (const float*)d_in[12];
  const float* W_hh = (const float*)d_in[13];
  const float* b_hh = (const float*)d_in[14];
  const float* W1 = (const float*)d_in[15];
  const float* b1 = (const float*)d_in[16];
  const float* W2 = (const float*)d_in[17];
  const float* b2 = (const float*)d_in[18];

  char* p = (char*)d_ws;
  auto alloc = [&](size_t bytes) { char* r = p; p += (bytes + 255) & ~(size_t)255; return r; };
  bf16_t* x_bf   = (bf16_t*)alloc((size_t)BB * NN * DD * 2);
  bf16_t* xT_bf  = (bf16_t*)alloc((size_t)BB * NN * DD * 2);
  bf16_t* GW_bf  = (bf16_t*)alloc(65536 * 2);
  bf16_t* Wihv_bf = (bf16_t*)alloc(196608 * 2);
  bf16_t* Whh_bf = (bf16_t*)alloc(196608 * 2);
  bf16_t* W1_bf  = (bf16_t*)alloc(131072 * 2);
  bf16_t* W2_bf  = (bf16_t*)alloc(131072 * 2);
  float* slots   = (float*)alloc((size_t)MR * DD * 4);
  bf16_t* q2_bf  = (bf16_t*)alloc((size_t)MR * DD * 2);
  bf16_t* att    = (bf16_t*)alloc((size_t)BB * KP * NN * 2);
  float* updR    = (float*)alloc((size_t)MR * DD * 4);
  float* rowsum  = (float*)alloc((size_t)MR * 4);

  conv3_k<<<1792, 256, 0, stream>>>(W_hh, W1, W2, Whh_bf, W1_bf, W2_bf);
  gw_k<<<256, 256, 0, stream>>>(Wq, Wk, GW_bf);
  wihv_k<<<768, 256, 0, stream>>>(W_ih, Wv, Wihv_bf);
  init_slots_k<<<1024, 256, 0, stream>>>(slots_in, slots);
  ln_tr_k<<<8192, 256, 0, stream>>>(inputs, ln_f_w, ln_f_b, x_bf, xT_bf);
  iter_k<0><<<64, 256, 0, stream>>>(updR, rowsum, slots, b_ih, b_hh, Wihv_bf, Whh_bf,
                                    W1_bf, b1, W2_bf, b2, ln_p_w, ln_p_b, ln_s_w, ln_s_b,
                                    GW_bf, q2_bf, nullptr, 0);
  for (int t = 0; t < 5; t++) {
    attn1_k<<<512, 256, 0, stream>>>(q2_bf, x_bf, att, rowsum);
    updates_k<<<512, 256, 0, stream>>>(att, xT_bf, updR);
    iter_k<1><<<64, 256, 0, stream>>>(updR, rowsum, slots, b_ih, b_hh, Wihv_bf, Whh_bf,
                                      W1_bf, b1, W2_bf, b2, ln_p_w, ln_p_b, ln_s_w, ln_s_b,
                                      GW_bf, q2_bf, (float*)d_out, t == 4);
  }
}